// Round 6
// baseline (865.074 us; speedup 1.0000x reference)
//
#include <hip/hip_runtime.h>
#include <math.h>

#define DM 256          // d_model
#define NS 64           // N state
#define SP 128          // spatial H == W

typedef __attribute__((ext_vector_type(8))) short bf16x8;
typedef __attribute__((ext_vector_type(4))) float f32x4;

__device__ __forceinline__ float gelu_f(float x) {
    float x3 = x * x * x;
    return 0.5f * x * (1.0f + tanhf(0.7978845608028654f * (x + 0.044715f * x3)));
}
__device__ __forceinline__ float sigmoid_f(float x) {
    return 1.0f / (1.0f + expf(-x));
}
__device__ __forceinline__ unsigned short f2bf(float f) {   // RNE f32->bf16
    unsigned u = __float_as_uint(f);
    u += 0x7fff + ((u >> 16) & 1);
    return (unsigned short)(u >> 16);
}
__device__ __forceinline__ float bf2f(unsigned short b) {
    return __uint_as_float(((unsigned)b) << 16);
}

// ---------------------------------------------------------------------------
// S4D tap generation -> Kd[la][d][q] fp32 (d-major taps, q in [0,128)).
// ---------------------------------------------------------------------------
__global__ __launch_bounds__(128) void gen_k_kernel(
        const float* __restrict__ log_dt, const float* __restrict__ logA_re,
        const float* __restrict__ A_im,   const float* __restrict__ C_re,
        const float* __restrict__ C_im,   float* __restrict__ Kd) {
    int blk = blockIdx.x;
    int d  = blk & (DM - 1);
    int la = blk >> 8;
    int q  = threadIdx.x;
    __shared__ float s_cbr[NS], s_cbi[NS], s_dr[NS], s_di[NS];
    int pbase = (la * DM + d) * NS;
    float dt = expf(log_dt[la * DM + d]);
    if (q < NS) {
        int n = q;
        float ar = -expf(logA_re[pbase + n]);
        float ai = A_im[pbase + n];
        float dr = dt * ar, di = dt * ai;
        float er = expf(dr);
        float sn, cs;
        sincosf(di, &sn, &cs);
        float nr = er * cs - 1.0f, ni = er * sn;
        float inv = 1.0f / (ar * ar + ai * ai);
        float br = (nr * ar + ni * ai) * inv;
        float bi = (ni * ar - nr * ai) * inv;
        float cr = C_re[pbase + n], ci = C_im[pbase + n];
        s_cbr[n] = cr * br - ci * bi;
        s_cbi[n] = cr * bi + ci * br;
        s_dr[n] = dr;
        s_di[n] = di;
    }
    __syncthreads();
    float fq = (float)q;
    float acc = 0.0f;
    for (int n = 0; n < NS; ++n) {
        float pr = expf(s_dr[n] * fq);
        float sn, cs;
        sincosf(s_di[n] * fq, &sn, &cs);
        acc += s_cbr[n] * (pr * cs) - s_cbi[n] * (pr * sn);
    }
    Kd[((size_t)la * DM + d) * SP + q] = 2.0f * acc;
}

// ---------------------------------------------------------------------------
// Toeplitz build (per layer): Tp[axis][d][i][j] = k_{l,axis,d}[i-j] (j<=i), bf16.
// grid 512 = axis*256 + d.
// ---------------------------------------------------------------------------
__global__ __launch_bounds__(256) void toep_kernel(
        const float* __restrict__ Kd, unsigned short* __restrict__ Tp, int l) {
    int blk = blockIdx.x;
    int axis = blk >> 8, d = blk & 255;
    int la = l * 2 + axis;
    __shared__ float kt[SP];
    if (threadIdx.x < SP) kt[threadIdx.x] = Kd[((size_t)la * DM + d) * SP + threadIdx.x];
    __syncthreads();
    size_t bse = ((size_t)axis * DM + d) * 16384;
    for (int e = threadIdx.x; e < 16384; e += 256) {
        int i = e >> 7, j = e & 127;
        Tp[bse + e] = (j <= i) ? f2bf(kt[i - j]) : (unsigned short)0;
    }
}

// ---------------------------------------------------------------------------
// W_out fp32 [l][k=256][n=512] -> Bt bf16 [l][n=512][k=256]
// ---------------------------------------------------------------------------
__global__ __launch_bounds__(256) void prep_b_kernel(
        const float* __restrict__ Wo, unsigned short* __restrict__ Bt) {
    int idx = blockIdx.x * 256 + threadIdx.x;
    int l = idx >> 17, rem = idx & 131071, n = rem >> 8, k = rem & 255;
    Bt[idx] = f2bf(Wo[(size_t)l * 131072 + k * 512 + n]);
}

// ---------------------------------------------------------------------------
// Encoder -> h_g[dg][pos][di] bf16 (group-of-8 channel-major).
// Block 256 = 4 waves; wave = 1 pos; lane = d-quad.
// ---------------------------------------------------------------------------
__global__ __launch_bounds__(256) void encode_kernel(
        const float* __restrict__ x, const float* __restrict__ g,
        const float* __restrict__ W_enc, const float* __restrict__ b_enc,
        unsigned short* __restrict__ hg) {
    int pos = blockIdx.x * 4 + (threadIdx.x >> 6);
    int lane = threadIdx.x & 63;
    int d0 = lane * 4;
    float xv = x[pos], gv = g[pos];
    float4 w0 = *(const float4*)(W_enc + d0);
    float4 w1 = *(const float4*)(W_enc + DM + d0);
    float4 bb = *(const float4*)(b_enc + d0);
    float v0 = xv * w0.x + gv * w1.x + bb.x;
    float v1 = xv * w0.y + gv * w1.y + bb.y;
    float v2 = xv * w0.z + gv * w1.z + bb.z;
    float v3 = xv * w0.w + gv * w1.w + bb.w;
    uint2 ov;
    ov.x = (unsigned)f2bf(v0) | ((unsigned)f2bf(v1) << 16);
    ov.y = (unsigned)f2bf(v2) | ((unsigned)f2bf(v3) << 16);
    *(uint2*)(hg + ((size_t)(d0 >> 3) * 65536 + pos) * 8 + (d0 & 7)) = ov;
}

// ---------------------------------------------------------------------------
// Fused separable conv via MFMA. WG = (d, b): Z_b = ToepH @ (U_b @ ToepW^T),
// epilogue A = gelu(Z + u*Dskip[d]).  4 waves, 64KB LDS (U + M1T), XOR-chunk
// swizzled tiles. XCD-grouped bid map so the 8 d-siblings of a group share
// cache lines for the 2B-strided h_g reads / A_g writes in one XCD's L2.
// Frag conventions (verified r2-r5): mfma(A,B,C): A lane&15=m-row, k contig;
// B lane&15=n-col, k contig; D col=lane&15, row=(lane>>4)*4+reg.
// ---------------------------------------------------------------------------
__global__ __launch_bounds__(256, 2) void conv_kernel(
        const unsigned short* __restrict__ hg, const unsigned short* __restrict__ Tp,
        unsigned short* __restrict__ Ag, const float* __restrict__ Dsk) {
    __shared__ unsigned short U[128][128];     // [hh][w-chunk ^ (hh&7)]
    __shared__ unsigned short M1T[128][128];   // [w][hh-chunk ^ (w&7)]
    int bid = blockIdx.x;
    int work = (bid & 7) * 128 + (bid >> 3);   // XCD-grouped
    int di = work & 7, rem = work >> 3;
    int b = rem & 3, dg = rem >> 2;
    int d = dg * 8 + di;
    int tid = threadIdx.x;
    int lane = tid & 63, wv = tid >> 6;
    int lc = lane & 15, g = lane >> 4;

    // ---- stage U from h_g (2B gathers at 16B stride; L2-merged across group)
    {
        const unsigned short* src = hg + ((size_t)dg * 65536 + (size_t)b * 16384) * 8 + di;
        for (int it = 0; it < 64; ++it) {
            int idx = it * 256 + tid;          // hh*128 + w
            int hh = idx >> 7, w = idx & 127;
            unsigned short v = src[(size_t)idx * 8];
            U[hh][(((w >> 3) ^ (hh & 7)) << 3) | (w & 7)] = v;
        }
    }
    __syncthreads();

    const unsigned short* TpW = Tp + (size_t)(DM + d) * 16384;  // axis 1 (W)
    const unsigned short* TpH = Tp + (size_t)d * 16384;         // axis 0 (H)

    // ---- GEMM1: M1[hh,w] = sum_j U[hh,j]*kw[w-j]  -> M1T[w][hh] (LDS)
    {
        f32x4 acc[2][8];
        #pragma unroll
        for (int mi = 0; mi < 2; ++mi)
            #pragma unroll
            for (int ni = 0; ni < 8; ++ni) acc[mi][ni] = (f32x4){0.f, 0.f, 0.f, 0.f};
        #pragma unroll
        for (int kk = 0; kk < 4; ++kk) {
            bf16x8 a[2];
            #pragma unroll
            for (int mi = 0; mi < 2; ++mi) {
                int hh = wv * 32 + mi * 16 + lc;
                a[mi] = *(const bf16x8*)&U[hh][(((kk * 4 + g) ^ (hh & 7)) << 3)];
            }
            #pragma unroll
            for (int ni = 0; ni < 8; ++ni) {
                bf16x8 bf = *(const bf16x8*)(TpW + (size_t)(ni * 16 + lc) * 128 + kk * 32 + g * 8);
                acc[0][ni] = __builtin_amdgcn_mfma_f32_16x16x32_bf16(a[0], bf, acc[0][ni], 0, 0, 0);
                acc[1][ni] = __builtin_amdgcn_mfma_f32_16x16x32_bf16(a[1], bf, acc[1][ni], 0, 0, 0);
            }
        }
        #pragma unroll
        for (int mi = 0; mi < 2; ++mi) {
            int hh0 = wv * 32 + mi * 16 + g * 4;
            #pragma unroll
            for (int ni = 0; ni < 8; ++ni) {
                int w = ni * 16 + lc;
                ushort4 p;
                p.x = f2bf(acc[mi][ni][0]); p.y = f2bf(acc[mi][ni][1]);
                p.z = f2bf(acc[mi][ni][2]); p.w = f2bf(acc[mi][ni][3]);
                *(ushort4*)&M1T[w][((((hh0 >> 3) ^ (w & 7)) << 3) | (hh0 & 7))] = p;
            }
        }
    }
    __syncthreads();

    // ---- GEMM2: ZT[w,hh] = sum_{h'} M1T[w,h']*kh[hh-h'] ; epilogue + store
    {
        f32x4 acc[2][8];
        #pragma unroll
        for (int mi = 0; mi < 2; ++mi)
            #pragma unroll
            for (int ni = 0; ni < 8; ++ni) acc[mi][ni] = (f32x4){0.f, 0.f, 0.f, 0.f};
        #pragma unroll
        for (int kk = 0; kk < 4; ++kk) {
            bf16x8 a[2];
            #pragma unroll
            for (int mi = 0; mi < 2; ++mi) {
                int w = wv * 32 + mi * 16 + lc;
                a[mi] = *(const bf16x8*)&M1T[w][(((kk * 4 + g) ^ (w & 7)) << 3)];
            }
            #pragma unroll
            for (int ni = 0; ni < 8; ++ni) {
                bf16x8 bf = *(const bf16x8*)(TpH + (size_t)(ni * 16 + lc) * 128 + kk * 32 + g * 8);
                acc[0][ni] = __builtin_amdgcn_mfma_f32_16x16x32_bf16(a[0], bf, acc[0][ni], 0, 0, 0);
                acc[1][ni] = __builtin_amdgcn_mfma_f32_16x16x32_bf16(a[1], bf, acc[1][ni], 0, 0, 0);
            }
        }
        float dk = Dsk[d];
        #pragma unroll
        for (int mi = 0; mi < 2; ++mi) {
            int w0 = wv * 32 + mi * 16 + g * 4;
            #pragma unroll
            for (int ni = 0; ni < 8; ++ni) {
                int hh = ni * 16 + lc;
                ushort4 hu = *(const ushort4*)&U[hh][((((w0 >> 3) ^ (hh & 7)) << 3) | (w0 & 7))];
                size_t ob = ((size_t)dg * 65536 + (size_t)b * 16384 + (size_t)hh * 128 + w0) * 8 + di;
                Ag[ob]      = f2bf(gelu_f(acc[mi][ni][0] + bf2f(hu.x) * dk));
                Ag[ob + 8]  = f2bf(gelu_f(acc[mi][ni][1] + bf2f(hu.y) * dk));
                Ag[ob + 16] = f2bf(gelu_f(acc[mi][ni][2] + bf2f(hu.z) * dk));
                Ag[ob + 24] = f2bf(gelu_f(acc[mi][ni][3] + bf2f(hu.w) * dk));
            }
        }
    }
}

// ---------------------------------------------------------------------------
// GLU GEMM, barrier/LDS-free (r5 structure): hp = (A@W_a+b_a)*sigmoid(A@W_g+b_g)+h
// A read from A_g (16B d-octet frags), residual from h_g, hp pos-major.
// ---------------------------------------------------------------------------
__global__ __launch_bounds__(512, 1) void glu_kernel(
        const unsigned short* __restrict__ Ag, const unsigned short* __restrict__ Bt,
        const unsigned short* __restrict__ hg, unsigned short* __restrict__ hp,
        const float* __restrict__ bo) {
    int tid = threadIdx.x;
    int lane = tid & 63, wv = tid >> 6;
    int lc = lane & 15, g = lane >> 4;
    int m0 = blockIdx.x * 128;

    bf16x8 wf[4][8];
    #pragma unroll
    for (int cf = 0; cf < 4; ++cf) {
        int colb = (cf < 2) ? (wv * 32 + cf * 16) : (256 + wv * 32 + (cf - 2) * 16);
        #pragma unroll
        for (int kk = 0; kk < 8; ++kk)
            wf[cf][kk] = *(const bf16x8*)(Bt + (size_t)(colb + lc) * DM + kk * 32 + g * 8);
    }
    float4 ba[2], bg[2];
    #pragma unroll
    for (int cf = 0; cf < 2; ++cf) {
        ba[cf] = *(const float4*)(bo + wv * 32 + cf * 16 + g * 4);
        bg[cf] = *(const float4*)(bo + 256 + wv * 32 + cf * 16 + g * 4);
    }

    bf16x8 af[8];
    #pragma unroll
    for (int kk = 0; kk < 8; ++kk)
        af[kk] = *(const bf16x8*)(Ag + ((size_t)(kk * 4 + g) * 65536 + m0 + lc) * 8);

    int d0 = wv * 32 + g * 4;
    size_t hoff0 = ((size_t)(d0 >> 3) * 65536) * 8 + (d0 & 7);
    size_t hoff1 = ((size_t)((d0 + 16) >> 3) * 65536) * 8 + (d0 & 7);

    #pragma unroll
    for (int s = 0; s < 8; ++s) {
        int pos = m0 + s * 16 + lc;
        uint2 hv0 = *(const uint2*)(hg + hoff0 + (size_t)pos * 8);
        uint2 hv1 = *(const uint2*)(hg + hoff1 + (size_t)pos * 8);

        f32x4 acc0 = (f32x4){0.f, 0.f, 0.f, 0.f};
        f32x4 acc1 = acc0, acc2 = acc0, acc3 = acc0;
        #pragma unroll
        for (int kk = 0; kk < 8; ++kk) {
            acc0 = __builtin_amdgcn_mfma_f32_16x16x32_bf16(wf[0][kk], af[kk], acc0, 0, 0, 0);
            acc1 = __builtin_amdgcn_mfma_f32_16x16x32_bf16(wf[1][kk], af[kk], acc1, 0, 0, 0);
            acc2 = __builtin_amdgcn_mfma_f32_16x16x32_bf16(wf[2][kk], af[kk], acc2, 0, 0, 0);
            acc3 = __builtin_amdgcn_mfma_f32_16x16x32_bf16(wf[3][kk], af[kk], acc3, 0, 0, 0);
            if (s < 7)
                af[kk] = *(const bf16x8*)(Ag + ((size_t)(kk * 4 + g) * 65536 + m0 + (s + 1) * 16 + lc) * 8);
        }

        float hr0[4], hr1[4];
        hr0[0] = __uint_as_float(hv0.x << 16);
        hr0[1] = __uint_as_float(hv0.x & 0xffff0000u);
        hr0[2] = __uint_as_float(hv0.y << 16);
        hr0[3] = __uint_as_float(hv0.y & 0xffff0000u);
        hr1[0] = __uint_as_float(hv1.x << 16);
        hr1[1] = __uint_as_float(hv1.x & 0xffff0000u);
        hr1[2] = __uint_as_float(hv1.y << 16);
        hr1[3] = __uint_as_float(hv1.y & 0xffff0000u);
        float o0[4], o1[4];
        #pragma unroll
        for (int reg = 0; reg < 4; ++reg) {
            o0[reg] = (acc0[reg] + (&ba[0].x)[reg]) * sigmoid_f(acc2[reg] + (&bg[0].x)[reg]) + hr0[reg];
            o1[reg] = (acc1[reg] + (&ba[1].x)[reg]) * sigmoid_f(acc3[reg] + (&bg[1].x)[reg]) + hr1[reg];
        }
        uint2 ov0, ov1;
        ov0.x = (unsigned)f2bf(o0[0]) | ((unsigned)f2bf(o0[1]) << 16);
        ov0.y = (unsigned)f2bf(o0[2]) | ((unsigned)f2bf(o0[3]) << 16);
        ov1.x = (unsigned)f2bf(o1[0]) | ((unsigned)f2bf(o1[1]) << 16);
        ov1.y = (unsigned)f2bf(o1[2]) | ((unsigned)f2bf(o1[3]) << 16);
        size_t pb = (size_t)pos * DM + wv * 32 + g * 4;
        *(uint2*)(hp + pb) = ov0;
        *(uint2*)(hp + pb + 16) = ov1;
    }
}

// ---------------------------------------------------------------------------
// LayerNorm: h_g = LN(hp).  Wave = 1 row (pos-major in, group-major out).
// ---------------------------------------------------------------------------
__global__ __launch_bounds__(256) void ln_kernel(
        const unsigned short* __restrict__ hp, unsigned short* __restrict__ hg,
        const float* __restrict__ lnw, const float* __restrict__ lnb) {
    int pos = blockIdx.x * 4 + (threadIdx.x >> 6);
    int lane = threadIdx.x & 63;
    size_t base = (size_t)pos * DM + lane * 4;
    uint2 hv = *(const uint2*)(hp + base);
    float v[4];
    v[0] = __uint_as_float(hv.x << 16);
    v[1] = __uint_as_float(hv.x & 0xffff0000u);
    v[2] = __uint_as_float(hv.y << 16);
    v[3] = __uint_as_float(hv.y & 0xffff0000u);
    float s1 = v[0] + v[1] + v[2] + v[3];
    float s2 = v[0] * v[0] + v[1] * v[1] + v[2] * v[2] + v[3] * v[3];
    #pragma unroll
    for (int off = 1; off < 64; off <<= 1) {
        s1 += __shfl_xor(s1, off);
        s2 += __shfl_xor(s2, off);
    }
    float mean = s1 * (1.0f / 256.0f);
    float var = s2 * (1.0f / 256.0f) - mean * mean;
    float inv = rsqrtf(var + 1e-5f);
    float4 w4 = *(const float4*)(lnw + lane * 4);
    float4 b4 = *(const float4*)(lnb + lane * 4);
    float o0 = (v[0] - mean) * inv * w4.x + b4.x;
    float o1 = (v[1] - mean) * inv * w4.y + b4.y;
    float o2 = (v[2] - mean) * inv * w4.z + b4.z;
    float o3 = (v[3] - mean) * inv * w4.w + b4.w;
    uint2 ov;
    ov.x = (unsigned)f2bf(o0) | ((unsigned)f2bf(o1) << 16);
    ov.y = (unsigned)f2bf(o2) | ((unsigned)f2bf(o3) << 16);
    int d0 = lane * 4;
    *(uint2*)(hg + ((size_t)(d0 >> 3) * 65536 + pos) * 8 + (d0 & 7)) = ov;
}

// ---------------------------------------------------------------------------
// Decoder from h_g.
// ---------------------------------------------------------------------------
__global__ __launch_bounds__(256) void decode_kernel(
        const unsigned short* __restrict__ hg, const float* __restrict__ Wd,
        const float* __restrict__ bd, float* __restrict__ out) {
    int pos = blockIdx.x * 4 + (threadIdx.x >> 6);
    int lane = threadIdx.x & 63;
    int d0 = lane * 4;
    uint2 hv = *(const uint2*)(hg + ((size_t)(d0 >> 3) * 65536 + pos) * 8 + (d0 & 7));
    float4 w4 = *(const float4*)(Wd + d0);
    float s = __uint_as_float(hv.x << 16) * w4.x
            + __uint_as_float(hv.x & 0xffff0000u) * w4.y
            + __uint_as_float(hv.y << 16) * w4.z
            + __uint_as_float(hv.y & 0xffff0000u) * w4.w;
    #pragma unroll
    for (int off = 32; off > 0; off >>= 1) s += __shfl_down(s, off);
    if (lane == 0) out[pos] = s + bd[0];
}

// ---------------------------------------------------------------------------
extern "C" void kernel_launch(void* const* d_in, const int* in_sizes, int n_in,
                              void* d_out, int out_size, void* d_ws, size_t ws_size,
                              hipStream_t stream) {
    const float* x       = (const float*)d_in[0];
    const float* grid    = (const float*)d_in[1];
    const float* W_enc   = (const float*)d_in[2];
    const float* b_enc   = (const float*)d_in[3];
    const float* log_dt  = (const float*)d_in[4];
    const float* logA_re = (const float*)d_in[5];
    const float* A_im    = (const float*)d_in[6];
    const float* C_re    = (const float*)d_in[7];
    const float* C_im    = (const float*)d_in[8];
    const float* Dskip   = (const float*)d_in[9];
    const float* W_out   = (const float*)d_in[10];
    const float* b_out   = (const float*)d_in[11];
    const float* ln_w    = (const float*)d_in[12];
    const float* ln_b    = (const float*)d_in[13];
    const float* W_dec   = (const float*)d_in[14];
    const float* b_dec   = (const float*)d_in[15];

    char* base = (char*)d_ws;
    float*          Kd  = (float*)base;                            //  1,048,576 B
    unsigned short* Bt  = (unsigned short*)(base + 1048576);       //  1,048,576 B
    unsigned short* hg  = (unsigned short*)(base + 2097152);       // 33,554,432 B
    unsigned short* Ag  = (unsigned short*)(base + 35651584);      // 33,554,432 B
    unsigned short* X   = (unsigned short*)(base + 69206016);      // 33,554,432 B
    unsigned short* Tp  = X;      // per-layer Toeplitz (16.78 MB of X)
    unsigned short* hp  = X;      // GLU output (33.55 MB) — time-shared with Tp

    gen_k_kernel<<<dim3(8 * DM), dim3(128), 0, stream>>>(log_dt, logA_re, A_im,
                                                         C_re, C_im, Kd);
    prep_b_kernel<<<dim3(2048), dim3(256), 0, stream>>>(W_out, Bt);
    encode_kernel<<<dim3(16384), dim3(256), 0, stream>>>(x, grid, W_enc, b_enc, hg);

    for (int l = 0; l < 4; ++l) {
        toep_kernel<<<dim3(512), dim3(256), 0, stream>>>(Kd, Tp, l);
        conv_kernel<<<dim3(1024), dim3(256), 0, stream>>>(hg, Tp, Ag,
                                                          Dskip + (size_t)l * DM);
        glu_kernel<<<dim3(512), dim3(512), 0, stream>>>(Ag,
            Bt + (size_t)l * 131072, hg, hp, b_out + (size_t)l * 512);
        ln_kernel<<<dim3(16384), dim3(256), 0, stream>>>(hp, hg,
            ln_w + (size_t)l * DM, ln_b + (size_t)l * DM);
    }

    decode_kernel<<<dim3(16384), dim3(256), 0, stream>>>(hg, W_dec, b_dec,
                                                         (float*)d_out);
}